// Round 3
// baseline (638.371 us; speedup 1.0000x reference)
//
#include <hip/hip_runtime.h>
#include <hip/hip_bf16.h>

#define CC 256
#define NN 4096
#define CQ 32
#define LOG2E 1.4426950408889634f

using short8 = __attribute__((ext_vector_type(8))) short;
using f32x4  = __attribute__((ext_vector_type(4))) float;

static __device__ __forceinline__ short f2bf(float f) {
  __hip_bfloat16 h = __float2bfloat16(f);
  return *reinterpret_cast<short*>(&h);
}

// ---------------------------------------------------------------------------
// Kernel 0: convert W (Wq|Wk|Wv rows concat) fp32 -> bf16 [320][256].
// ---------------------------------------------------------------------------
__global__ __launch_bounds__(256) void prep_kernel(
    const float* __restrict__ Wq, const float* __restrict__ Wk,
    const float* __restrict__ Wv, __hip_bfloat16* __restrict__ Wb)
{
  int e0 = (blockIdx.x*256 + threadIdx.x) * 8;   // 0..81912
  const float* src;
  if (e0 < 32*CC)       src = Wq + e0;
  else if (e0 < 64*CC)  src = Wk + (e0 - 32*CC);
  else                  src = Wv + (e0 - 64*CC);
  float4 a = *(const float4*)(src);
  float4 c = *(const float4*)(src + 4);
  short8 o;
  o[0]=f2bf(a.x); o[1]=f2bf(a.y); o[2]=f2bf(a.z); o[3]=f2bf(a.w);
  o[4]=f2bf(c.x); o[5]=f2bf(c.y); o[6]=f2bf(c.z); o[7]=f2bf(c.w);
  *reinterpret_cast<short8*>(reinterpret_cast<short*>(Wb) + e0) = o;
}

// ---------------------------------------------------------------------------
// Kernel 1: QKV via MFMA, x-stationary.  Block = 64 n x all 320 rows.
// Stage x[256c x 64n] once -> LDS bf16 [n][c] (B-operand layout), then
// 20 r-tiles x 4 n-tiles x 8 k-chunks of 16x16x32 MFMA.
// q -> qb[b][n][32] (scaled by LOG2E), k -> kb[b][m][32], v -> vb[b][c][n].
// ---------------------------------------------------------------------------
__global__ __launch_bounds__(256) void qkv_kernel(
    const float* __restrict__ x, const __hip_bfloat16* __restrict__ Wb,
    const float* __restrict__ bq, const float* __restrict__ bk,
    const float* __restrict__ bv,
    __hip_bfloat16* __restrict__ qb, __hip_bfloat16* __restrict__ kb,
    __hip_bfloat16* __restrict__ vb)
{
  const int b  = blockIdx.y;
  const int n0 = blockIdx.x * 64;
  const int tid = threadIdx.x;
  const int lane = tid & 63;
  const int w = __builtin_amdgcn_readfirstlane(tid >> 6);  // wave 0..3
  const int l15 = lane & 15, quad = lane >> 4;

  __shared__ __align__(16) short Xs[64][264];   // [n][c], stride 264 keeps 16B align

  // stage x-tile: wave w covers c in [w*64, w*64+64), lanes cover all 64 n
  const float* xrow = x + (size_t)b*CC*NN + n0 + lane;
  for (int cc8 = 0; cc8 < 8; cc8++) {
    int cbase = w*64 + cc8*8;
    float v[8];
#pragma unroll
    for (int j = 0; j < 8; j++) v[j] = xrow[(size_t)(cbase + j)*NN];
    short8 sv;
#pragma unroll
    for (int j = 0; j < 8; j++) sv[j] = f2bf(v[j]);
    *reinterpret_cast<short8*>(&Xs[lane][cbase]) = sv;
  }
  __syncthreads();

  const short* wbp = reinterpret_cast<const short*>(Wb);

  for (int jt = 0; jt < 5; jt++) {
    const int rt = w + 4*jt;          // r-tile 0..19 (0,1=q; 2,3=k; 4..19=v)
    short8 Af[8];
#pragma unroll
    for (int kc = 0; kc < 8; kc++)
      Af[kc] = *reinterpret_cast<const short8*>(
          wbp + (size_t)(rt*16 + l15)*CC + kc*32 + quad*8);

    for (int nt = 0; nt < 4; nt++) {
      f32x4 acc = {0.f,0.f,0.f,0.f};
#pragma unroll
      for (int kc = 0; kc < 8; kc++) {
        short8 Bf = *reinterpret_cast<const short8*>(&Xs[nt*16 + l15][kc*32 + quad*8]);
        acc = __builtin_amdgcn_mfma_f32_16x16x32_bf16(Af[kc], Bf, acc, 0, 0, 0);
      }
      // D[row = quad*4+r : r-offset][col = l15 : n-offset]
      const int nn = n0 + nt*16 + l15;
      if (rt < 2) {
#pragma unroll
        for (int r = 0; r < 4; r++) {
          int d = rt*16 + quad*4 + r;
          qb[(size_t)b*NN*CQ + (size_t)nn*CQ + d] =
              __float2bfloat16(LOG2E*(acc[r] + bq[d]));
        }
      } else if (rt < 4) {
#pragma unroll
        for (int r = 0; r < 4; r++) {
          int d = (rt-2)*16 + quad*4 + r;
          kb[(size_t)b*NN*CQ + (size_t)nn*CQ + d] =
              __float2bfloat16(acc[r] + bk[d]);
        }
      } else {
#pragma unroll
        for (int r = 0; r < 4; r++) {
          int rv = (rt-4)*16 + quad*4 + r;
          vb[((size_t)b*CC + rv)*NN + nn] = __float2bfloat16(acc[r] + bv[rv]);
        }
      }
    }
  }
}

// ---------------------------------------------------------------------------
// Kernel 2: O = softmax(QK^T) V, epilogue gamma*O + x.
// 512 threads = 8 waves: waves 0-3 process even 32-m tiles, 4-7 odd tiles
// (m-parity split -> 2 waves/SIMD to hide LDS latency).  Per-wave machinery
// identical to the verified round-2 kernel.  Partial O / row-sums combined
// via LDS at the end.  Single V tile-pair buffer, 2 barriers/iter,
// register prefetch of the next pair.  XCD swizzle: one batch per XCD.
// ---------------------------------------------------------------------------
__global__ __launch_bounds__(512) void attn_kernel(
    const __hip_bfloat16* __restrict__ qb, const __hip_bfloat16* __restrict__ kb,
    const __hip_bfloat16* __restrict__ vb,
    const float* __restrict__ x, const float* __restrict__ gamma,
    float* __restrict__ out)
{
  const int B = blockIdx.x;
  const int b = (B & 7) >> 1;                       // batch: 2 XCDs per batch
  const int n0 = ((B >> 3)*2 + (B & 1)) * 64;       // n-tile 0..63
  const int tid = threadIdx.x;
  const int lane = tid & 63;
  const int w = __builtin_amdgcn_readfirstlane(tid >> 6);   // 0..7
  const int p = w >> 2;                              // m-parity
  const int wn = w & 3;                              // n-group
  const int l15 = lane & 15, quad = lane >> 4;
  const int nw = n0 + wn*16;

  // LDS pool: Vs[2][256][40] shorts (40960 B) + Ps[128][40] (10240 B)
  __shared__ __align__(16) short pool[25600];
  short (*Vs)[256][40] = reinterpret_cast<short(*)[256][40]>(&pool[0]);
  short (*Ps)[40]      = reinterpret_cast<short(*)[40]>(&pool[20480]);

  const short* qbase = (const short*)qb + (size_t)b*NN*CQ;
  const short* kbase = (const short*)kb + (size_t)b*NN*CQ;
  const short* vbase = (const short*)vb + (size_t)b*CC*NN;

  short8 aq = *(const short8*)(qbase + (size_t)(nw + l15)*CQ + quad*8);

  const int c_st = tid >> 1, h_st = tid & 1;   // V staging: 4x16B per thread

  // preload tile pair 0 (tiles 0,1)
#pragma unroll
  for (int j = 0; j < 4; j++) {
    int s = j >> 1, mb = h_st*2 + (j & 1);
    *(short8*)(&Vs[s][c_st][mb*8]) =
        *(const short8*)(vbase + (size_t)c_st*NN + s*32 + mb*8);
  }
  short8 kf0 = *(const short8*)(kbase + (size_t)(p*32 + l15)*CQ + quad*8);
  short8 kf1 = *(const short8*)(kbase + (size_t)(p*32 + 16 + l15)*CQ + quad*8);

  f32x4 acc[16];
#pragma unroll
  for (int cc = 0; cc < 16; cc++) acc[cc] = (f32x4){0.f,0.f,0.f,0.f};
  float lsum[4] = {0.f,0.f,0.f,0.f};

  __syncthreads();

  for (int i = 0; i < 64; i++) {
    // prefetch next pair into regs (latency hidden under compute)
    short8 nv0, nv1, nv2, nv3, nk0, nk1;
    if (i < 63) {
      int mbase = (2*i + 2)*32;
      int mb0 = h_st*2;
      nv0 = *(const short8*)(vbase + (size_t)c_st*NN + mbase      + mb0*8);
      nv1 = *(const short8*)(vbase + (size_t)c_st*NN + mbase      + (mb0+1)*8);
      nv2 = *(const short8*)(vbase + (size_t)c_st*NN + mbase + 32 + mb0*8);
      nv3 = *(const short8*)(vbase + (size_t)c_st*NN + mbase + 32 + (mb0+1)*8);
      int mk = (2*(i+1) + p)*32;
      nk0 = *(const short8*)(kbase + (size_t)(mk + l15)*CQ + quad*8);
      nk1 = *(const short8*)(kbase + (size_t)(mk + 16 + l15)*CQ + quad*8);
    }

    // S' = (log2e q) k^T for my tile T = 2i+p
    f32x4 z = {0.f,0.f,0.f,0.f};
    f32x4 S0 = __builtin_amdgcn_mfma_f32_16x16x32_bf16(aq, kf0, z, 0,0,0);
    f32x4 S1 = __builtin_amdgcn_mfma_f32_16x16x32_bf16(aq, kf1, z, 0,0,0);

    const int rowp = w*16 + quad*4;
#pragma unroll
    for (int r = 0; r < 4; r++) {
      float e0 = __builtin_amdgcn_exp2f(S0[r]);
      float e1 = __builtin_amdgcn_exp2f(S1[r]);
      lsum[r] += e0 + e1;
      Ps[rowp + r][l15]      = f2bf(e0);
      Ps[rowp + r][16 + l15] = f2bf(e1);
    }
    short8 ap = *(const short8*)(&Ps[w*16 + l15][quad*8]);  // wave-private

#pragma unroll
    for (int cc = 0; cc < 16; cc++) {
      short8 bv8 = *(const short8*)(&Vs[p][cc*16 + l15][quad*8]);
      acc[cc] = __builtin_amdgcn_mfma_f32_16x16x32_bf16(ap, bv8, acc[cc], 0,0,0);
    }

    __syncthreads();                 // all waves done reading Vs pair i
    if (i < 63) {
      int mb0 = h_st*2;
      *(short8*)(&Vs[0][c_st][mb0*8])     = nv0;
      *(short8*)(&Vs[0][c_st][(mb0+1)*8]) = nv1;
      *(short8*)(&Vs[1][c_st][mb0*8])     = nv2;
      *(short8*)(&Vs[1][c_st][(mb0+1)*8]) = nv3;
      kf0 = nk0; kf1 = nk1;
    }
    __syncthreads();                 // pair i+1 visible
  }

  // ---- combine parity halves: p1 -> p0 via LDS (2 rounds of 8 cc) ----
  float* poolf = reinterpret_cast<float*>(pool);
  __syncthreads();
#pragma unroll 1
  for (int gg = 0; gg < 2; gg++) {
    if (p == 1) {
#pragma unroll
      for (int j = 0; j < 8; j++)
#pragma unroll
        for (int r = 0; r < 4; r++)
          poolf[wn*2048 + (j*4+r)*64 + lane] = acc[gg*8+j][r];
    }
    __syncthreads();
    if (p == 0) {
#pragma unroll
      for (int j = 0; j < 8; j++)
#pragma unroll
        for (int r = 0; r < 4; r++)
          acc[gg*8+j][r] += poolf[wn*2048 + (j*4+r)*64 + lane];
    }
    __syncthreads();
  }
  if (p == 1) {
#pragma unroll
    for (int r = 0; r < 4; r++) poolf[8192 + wn*256 + r*64 + lane] = lsum[r];
  }
  __syncthreads();
  float Li[4] = {0.f,0.f,0.f,0.f};
  if (p == 0) {
#pragma unroll
    for (int r = 0; r < 4; r++) {
      float s = lsum[r] + poolf[8192 + wn*256 + r*64 + lane];
      s += __shfl_xor(s, 1); s += __shfl_xor(s, 2);
      s += __shfl_xor(s, 4); s += __shfl_xor(s, 8);
      Li[r] = 1.0f / s;
    }
  }
  __syncthreads();

  // ---- epilogue: out[b][c][n] = gamma*O[n][c]/l[n] + x[b][c][n] ----
  float (*Es)[16][67] = reinterpret_cast<float(*)[16][67]>(poolf);
  const float gm = gamma[0];
#pragma unroll 1
  for (int cg = 0; cg < 4; cg++) {
    __syncthreads();
    if (p == 0) {
#pragma unroll
      for (int c2 = 0; c2 < 4; c2++)
#pragma unroll
        for (int r = 0; r < 4; r++)
          Es[c2][l15][wn*16 + quad*4 + r] = acc[cg*4 + c2][r] * Li[r];
    }
    __syncthreads();
#pragma unroll
    for (int k2 = 0; k2 < 8; k2++) {
      int e = tid + k2*512;
      int row = e >> 6, nn2 = e & 63;
      size_t idx = ((size_t)b*CC + cg*64 + row)*NN + n0 + nn2;
      out[idx] = gm * Es[row >> 4][row & 15][nn2] + x[idx];
    }
  }
}

// ---------------------------------------------------------------------------
extern "C" void kernel_launch(void* const* d_in, const int* in_sizes, int n_in,
                              void* d_out, int out_size, void* d_ws, size_t ws_size,
                              hipStream_t stream) {
  const float* x     = (const float*)d_in[0];
  const float* Wq    = (const float*)d_in[1];
  const float* bq    = (const float*)d_in[2];
  const float* Wk    = (const float*)d_in[3];
  const float* bk    = (const float*)d_in[4];
  const float* Wv    = (const float*)d_in[5];
  const float* bv    = (const float*)d_in[6];
  const float* gamma = (const float*)d_in[7];
  float* out = (float*)d_out;

  char* ws = (char*)d_ws;
  if (ws_size < (11u << 20)) return;
  __hip_bfloat16* qb = (__hip_bfloat16*)(ws);                 // [B][N][32]  1 MB
  __hip_bfloat16* kb = (__hip_bfloat16*)(ws + (1u << 20));    // [B][N][32]  1 MB
  __hip_bfloat16* vb = (__hip_bfloat16*)(ws + (2u << 20));    // [B][C][N]   8 MB
  __hip_bfloat16* Wb = (__hip_bfloat16*)(ws + (10u << 20));   // [320][256]  160 KB

  prep_kernel<<<dim3(40), 256, 0, stream>>>(Wq, Wk, Wv, Wb);
  qkv_kernel<<<dim3(64, 4), 256, 0, stream>>>(x, Wb, bq, bk, bv, qb, kb, vb);
  attn_kernel<<<dim3(256), 512, 0, stream>>>(qb, kb, vb, x, gamma, out);
}

// Round 4
// 181.296 us; speedup vs baseline: 3.5212x; 3.5212x over previous
//
#include <hip/hip_runtime.h>
#include <hip/hip_bf16.h>

#define CC 256
#define NN 4096
#define CQ 32
#define LOG2E 1.4426950408889634f

using short8 = __attribute__((ext_vector_type(8))) short;
using f32x4  = __attribute__((ext_vector_type(4))) float;

static __device__ __forceinline__ short f2bf(float f) {
  __hip_bfloat16 h = __float2bfloat16(f);
  return *reinterpret_cast<short*>(&h);
}

// ---------------------------------------------------------------------------
// Kernel 0: convert W (Wq|Wk|Wv rows concat) fp32 -> bf16 [320][256].
// ---------------------------------------------------------------------------
__global__ __launch_bounds__(256) void prep_kernel(
    const float* __restrict__ Wq, const float* __restrict__ Wk,
    const float* __restrict__ Wv, __hip_bfloat16* __restrict__ Wb)
{
  int e0 = (blockIdx.x*256 + threadIdx.x) * 8;   // 0..81912
  const float* src;
  if (e0 < 32*CC)       src = Wq + e0;
  else if (e0 < 64*CC)  src = Wk + (e0 - 32*CC);
  else                  src = Wv + (e0 - 64*CC);
  float4 a = *(const float4*)(src);
  float4 c = *(const float4*)(src + 4);
  short8 o;
  o[0]=f2bf(a.x); o[1]=f2bf(a.y); o[2]=f2bf(a.z); o[3]=f2bf(a.w);
  o[4]=f2bf(c.x); o[5]=f2bf(c.y); o[6]=f2bf(c.z); o[7]=f2bf(c.w);
  *reinterpret_cast<short8*>(reinterpret_cast<short*>(Wb) + e0) = o;
}

// ---------------------------------------------------------------------------
// Kernel 1: QKV via MFMA, x-stationary.  Block = 64 n x all 320 rows.
// Stage x[256c x 64n] once -> LDS bf16 [n][c] (B-operand layout), then
// 20 r-tiles x 4 n-tiles x 8 k-chunks of 16x16x32 MFMA.
// q -> qb[b][n][32] (scaled by LOG2E), k -> kb[b][m][32], v -> vb[b][c][n].
// ---------------------------------------------------------------------------
__global__ __launch_bounds__(256) void qkv_kernel(
    const float* __restrict__ x, const __hip_bfloat16* __restrict__ Wb,
    const float* __restrict__ bq, const float* __restrict__ bk,
    const float* __restrict__ bv,
    __hip_bfloat16* __restrict__ qb, __hip_bfloat16* __restrict__ kb,
    __hip_bfloat16* __restrict__ vb)
{
  const int b  = blockIdx.y;
  const int n0 = blockIdx.x * 64;
  const int tid = threadIdx.x;
  const int lane = tid & 63;
  const int w = __builtin_amdgcn_readfirstlane(tid >> 6);  // wave 0..3
  const int l15 = lane & 15, quad = lane >> 4;

  __shared__ __align__(16) short Xs[64][264];   // [n][c], stride 264 keeps 16B align

  // stage x-tile: wave w covers c in [w*64, w*64+64), lanes cover all 64 n
  const float* xrow = x + (size_t)b*CC*NN + n0 + lane;
  for (int cc8 = 0; cc8 < 8; cc8++) {
    int cbase = w*64 + cc8*8;
    float v[8];
#pragma unroll
    for (int j = 0; j < 8; j++) v[j] = xrow[(size_t)(cbase + j)*NN];
    short8 sv;
#pragma unroll
    for (int j = 0; j < 8; j++) sv[j] = f2bf(v[j]);
    *reinterpret_cast<short8*>(&Xs[lane][cbase]) = sv;
  }
  __syncthreads();

  const short* wbp = reinterpret_cast<const short*>(Wb);

  for (int jt = 0; jt < 5; jt++) {
    const int rt = w + 4*jt;          // r-tile 0..19 (0,1=q; 2,3=k; 4..19=v)
    short8 Af[8];
#pragma unroll
    for (int kc = 0; kc < 8; kc++)
      Af[kc] = *reinterpret_cast<const short8*>(
          wbp + (size_t)(rt*16 + l15)*CC + kc*32 + quad*8);

    for (int nt = 0; nt < 4; nt++) {
      f32x4 acc = {0.f,0.f,0.f,0.f};
#pragma unroll
      for (int kc = 0; kc < 8; kc++) {
        short8 Bf = *reinterpret_cast<const short8*>(&Xs[nt*16 + l15][kc*32 + quad*8]);
        acc = __builtin_amdgcn_mfma_f32_16x16x32_bf16(Af[kc], Bf, acc, 0, 0, 0);
      }
      // D[row = quad*4+r : r-offset][col = l15 : n-offset]
      const int nn = n0 + nt*16 + l15;
      if (rt < 2) {
#pragma unroll
        for (int r = 0; r < 4; r++) {
          int d = rt*16 + quad*4 + r;
          qb[(size_t)b*NN*CQ + (size_t)nn*CQ + d] =
              __float2bfloat16(LOG2E*(acc[r] + bq[d]));
        }
      } else if (rt < 4) {
#pragma unroll
        for (int r = 0; r < 4; r++) {
          int d = (rt-2)*16 + quad*4 + r;
          kb[(size_t)b*NN*CQ + (size_t)nn*CQ + d] =
              __float2bfloat16(acc[r] + bk[d]);
        }
      } else {
#pragma unroll
        for (int r = 0; r < 4; r++) {
          int rv = (rt-4)*16 + quad*4 + r;
          vb[((size_t)b*CC + rv)*NN + nn] = __float2bfloat16(acc[r] + bv[rv]);
        }
      }
    }
  }
}

// ---------------------------------------------------------------------------
// Kernel 2: O = softmax(QK^T) V, epilogue gamma*O + x.
// 512 threads = 8 waves: waves 0-3 process even 32-m tiles, 4-7 odd tiles
// (m-parity split -> 2 waves/SIMD to hide LDS latency).  Partial O /
// row-sums combined via LDS at the end.  Single V tile-pair buffer,
// 2 barriers/iter, register prefetch of the next pair.
// NOTE: every acc[] subscript must be a compile-time constant (full unroll)
// or the 64-reg accumulator spills to scratch (round-1/round-3 bug:
// VGPR_Count drops to ~52, WRITE_SIZE explodes to GBs).
// ---------------------------------------------------------------------------
__global__ __launch_bounds__(512) void attn_kernel(
    const __hip_bfloat16* __restrict__ qb, const __hip_bfloat16* __restrict__ kb,
    const __hip_bfloat16* __restrict__ vb,
    const float* __restrict__ x, const float* __restrict__ gamma,
    float* __restrict__ out)
{
  const int B = blockIdx.x;
  const int b = (B & 7) >> 1;                       // batch: 2 XCDs per batch
  const int n0 = ((B >> 3)*2 + (B & 1)) * 64;       // n-tile 0..63
  const int tid = threadIdx.x;
  const int lane = tid & 63;
  const int w = __builtin_amdgcn_readfirstlane(tid >> 6);   // 0..7
  const int p = w >> 2;                              // m-parity
  const int wn = w & 3;                              // n-group
  const int l15 = lane & 15, quad = lane >> 4;
  const int nw = n0 + wn*16;

  // LDS pool: Vs[2][256][40] shorts (40960 B) + Ps[128][40] (10240 B)
  __shared__ __align__(16) short pool[25600];
  short (*Vs)[256][40] = reinterpret_cast<short(*)[256][40]>(&pool[0]);
  short (*Ps)[40]      = reinterpret_cast<short(*)[40]>(&pool[20480]);

  const short* qbase = (const short*)qb + (size_t)b*NN*CQ;
  const short* kbase = (const short*)kb + (size_t)b*NN*CQ;
  const short* vbase = (const short*)vb + (size_t)b*CC*NN;

  short8 aq = *(const short8*)(qbase + (size_t)(nw + l15)*CQ + quad*8);

  const int c_st = tid >> 1, h_st = tid & 1;   // V staging: 4x16B per thread

  // preload tile pair 0 (tiles 0,1)
#pragma unroll
  for (int j = 0; j < 4; j++) {
    int s = j >> 1, mb = h_st*2 + (j & 1);
    *(short8*)(&Vs[s][c_st][mb*8]) =
        *(const short8*)(vbase + (size_t)c_st*NN + s*32 + mb*8);
  }
  short8 kf0 = *(const short8*)(kbase + (size_t)(p*32 + l15)*CQ + quad*8);
  short8 kf1 = *(const short8*)(kbase + (size_t)(p*32 + 16 + l15)*CQ + quad*8);

  f32x4 acc[16];
#pragma unroll
  for (int cc = 0; cc < 16; cc++) acc[cc] = (f32x4){0.f,0.f,0.f,0.f};
  float lsum[4] = {0.f,0.f,0.f,0.f};

  __syncthreads();

  for (int i = 0; i < 64; i++) {
    // prefetch next pair into regs (latency hidden under compute)
    short8 nv0, nv1, nv2, nv3, nk0, nk1;
    if (i < 63) {
      int mbase = (2*i + 2)*32;
      int mb0 = h_st*2;
      nv0 = *(const short8*)(vbase + (size_t)c_st*NN + mbase      + mb0*8);
      nv1 = *(const short8*)(vbase + (size_t)c_st*NN + mbase      + (mb0+1)*8);
      nv2 = *(const short8*)(vbase + (size_t)c_st*NN + mbase + 32 + mb0*8);
      nv3 = *(const short8*)(vbase + (size_t)c_st*NN + mbase + 32 + (mb0+1)*8);
      int mk = (2*(i+1) + p)*32;
      nk0 = *(const short8*)(kbase + (size_t)(mk + l15)*CQ + quad*8);
      nk1 = *(const short8*)(kbase + (size_t)(mk + 16 + l15)*CQ + quad*8);
    }

    // S' = (log2e q) k^T for my tile T = 2i+p
    f32x4 z = {0.f,0.f,0.f,0.f};
    f32x4 S0 = __builtin_amdgcn_mfma_f32_16x16x32_bf16(aq, kf0, z, 0,0,0);
    f32x4 S1 = __builtin_amdgcn_mfma_f32_16x16x32_bf16(aq, kf1, z, 0,0,0);

    const int rowp = w*16 + quad*4;
#pragma unroll
    for (int r = 0; r < 4; r++) {
      float e0 = __builtin_amdgcn_exp2f(S0[r]);
      float e1 = __builtin_amdgcn_exp2f(S1[r]);
      lsum[r] += e0 + e1;
      Ps[rowp + r][l15]      = f2bf(e0);
      Ps[rowp + r][16 + l15] = f2bf(e1);
    }
    short8 ap = *(const short8*)(&Ps[w*16 + l15][quad*8]);  // wave-private

#pragma unroll
    for (int cc = 0; cc < 16; cc++) {
      short8 bv8 = *(const short8*)(&Vs[p][cc*16 + l15][quad*8]);
      acc[cc] = __builtin_amdgcn_mfma_f32_16x16x32_bf16(ap, bv8, acc[cc], 0,0,0);
    }

    __syncthreads();                 // all waves done reading Vs pair i
    if (i < 63) {
      int mb0 = h_st*2;
      *(short8*)(&Vs[0][c_st][mb0*8])     = nv0;
      *(short8*)(&Vs[0][c_st][(mb0+1)*8]) = nv1;
      *(short8*)(&Vs[1][c_st][mb0*8])     = nv2;
      *(short8*)(&Vs[1][c_st][(mb0+1)*8]) = nv3;
      kf0 = nk0; kf1 = nk1;
    }
    __syncthreads();                 // pair i+1 visible
  }

  // ---- combine parity halves: p1 -> p0 via LDS (FULLY UNROLLED: constant
  //      acc[] subscripts only, else the accumulator spills to scratch) ----
  float* poolf = reinterpret_cast<float*>(pool);
  __syncthreads();
#pragma unroll
  for (int gg = 0; gg < 2; gg++) {
    if (p == 1) {
#pragma unroll
      for (int j = 0; j < 8; j++)
#pragma unroll
        for (int r = 0; r < 4; r++)
          poolf[wn*2048 + (j*4+r)*64 + lane] = acc[gg*8+j][r];
    }
    __syncthreads();
    if (p == 0) {
#pragma unroll
      for (int j = 0; j < 8; j++)
#pragma unroll
        for (int r = 0; r < 4; r++)
          acc[gg*8+j][r] += poolf[wn*2048 + (j*4+r)*64 + lane];
    }
    __syncthreads();
  }
  if (p == 1) {
#pragma unroll
    for (int r = 0; r < 4; r++) poolf[8192 + wn*256 + r*64 + lane] = lsum[r];
  }
  __syncthreads();
  float Li[4] = {0.f,0.f,0.f,0.f};
  if (p == 0) {
#pragma unroll
    for (int r = 0; r < 4; r++) {
      float s = lsum[r] + poolf[8192 + wn*256 + r*64 + lane];
      s += __shfl_xor(s, 1); s += __shfl_xor(s, 2);
      s += __shfl_xor(s, 4); s += __shfl_xor(s, 8);
      Li[r] = 1.0f / s;
    }
  }
  __syncthreads();

  // ---- epilogue: out[b][c][n] = gamma*O[n][c]/l[n] + x[b][c][n] ----
  // (cg loop FULLY UNROLLED for constant acc[] subscripts)
  float (*Es)[16][67] = reinterpret_cast<float(*)[16][67]>(poolf);
  const float gm = gamma[0];
#pragma unroll
  for (int cg = 0; cg < 4; cg++) {
    __syncthreads();
    if (p == 0) {
#pragma unroll
      for (int c2 = 0; c2 < 4; c2++)
#pragma unroll
        for (int r = 0; r < 4; r++)
          Es[c2][l15][wn*16 + quad*4 + r] = acc[cg*4 + c2][r] * Li[r];
    }
    __syncthreads();
#pragma unroll
    for (int k2 = 0; k2 < 8; k2++) {
      int e = tid + k2*512;
      int row = e >> 6, nn2 = e & 63;
      size_t idx = ((size_t)b*CC + cg*64 + row)*NN + n0 + nn2;
      out[idx] = gm * Es[row >> 4][row & 15][nn2] + x[idx];
    }
  }
}

// ---------------------------------------------------------------------------
extern "C" void kernel_launch(void* const* d_in, const int* in_sizes, int n_in,
                              void* d_out, int out_size, void* d_ws, size_t ws_size,
                              hipStream_t stream) {
  const float* x     = (const float*)d_in[0];
  const float* Wq    = (const float*)d_in[1];
  const float* bq    = (const float*)d_in[2];
  const float* Wk    = (const float*)d_in[3];
  const float* bk    = (const float*)d_in[4];
  const float* Wv    = (const float*)d_in[5];
  const float* bv    = (const float*)d_in[6];
  const float* gamma = (const float*)d_in[7];
  float* out = (float*)d_out;

  char* ws = (char*)d_ws;
  if (ws_size < (11u << 20)) return;
  __hip_bfloat16* qb = (__hip_bfloat16*)(ws);                 // [B][N][32]  1 MB
  __hip_bfloat16* kb = (__hip_bfloat16*)(ws + (1u << 20));    // [B][N][32]  1 MB
  __hip_bfloat16* vb = (__hip_bfloat16*)(ws + (2u << 20));    // [B][C][N]   8 MB
  __hip_bfloat16* Wb = (__hip_bfloat16*)(ws + (10u << 20));   // [320][256]  160 KB

  prep_kernel<<<dim3(40), 256, 0, stream>>>(Wq, Wk, Wv, Wb);
  qkv_kernel<<<dim3(64, 4), 256, 0, stream>>>(x, Wb, bq, bk, bv, qb, kb, vb);
  attn_kernel<<<dim3(256), 512, 0, stream>>>(qb, kb, vb, x, gamma, out);
}

// Round 5
// 177.875 us; speedup vs baseline: 3.5889x; 1.0192x over previous
//
#include <hip/hip_runtime.h>
#include <hip/hip_bf16.h>

#define CC 256
#define NN 4096
#define CQ 32
#define LOG2E 1.4426950408889634f

using short8 = __attribute__((ext_vector_type(8))) short;
using f32x4  = __attribute__((ext_vector_type(4))) float;

static __device__ __forceinline__ short f2bf(float f) {
  __hip_bfloat16 h = __float2bfloat16(f);
  return *reinterpret_cast<short*>(&h);
}

// ---------------------------------------------------------------------------
// Kernel 0: convert W (Wq|Wk|Wv rows concat) fp32 -> bf16 [320][256].
// ---------------------------------------------------------------------------
__global__ __launch_bounds__(256) void prep_kernel(
    const float* __restrict__ Wq, const float* __restrict__ Wk,
    const float* __restrict__ Wv, __hip_bfloat16* __restrict__ Wb)
{
  int e0 = (blockIdx.x*256 + threadIdx.x) * 8;   // 0..81912
  const float* src;
  if (e0 < 32*CC)       src = Wq + e0;
  else if (e0 < 64*CC)  src = Wk + (e0 - 32*CC);
  else                  src = Wv + (e0 - 64*CC);
  float4 a = *(const float4*)(src);
  float4 c = *(const float4*)(src + 4);
  short8 o;
  o[0]=f2bf(a.x); o[1]=f2bf(a.y); o[2]=f2bf(a.z); o[3]=f2bf(a.w);
  o[4]=f2bf(c.x); o[5]=f2bf(c.y); o[6]=f2bf(c.z); o[7]=f2bf(c.w);
  *reinterpret_cast<short8*>(reinterpret_cast<short*>(Wb) + e0) = o;
}

// ---------------------------------------------------------------------------
// Kernel 1: QKV via MFMA, x-stationary.  n-tile 32 -> grid 512 = 2 blocks/CU
// (round-4 ran 1 wave/SIMD: everything latency-exposed).  Per block: stage
// x[256c x 32n] -> LDS bf16 [n][c], 20 r-tiles x 2 n-tiles x 8 MFMA.
// v output repacked via wave-private LDS -> one dwordx4 store per r-tile
// (64B row segments) instead of 16 scattered 2B-per-lane stores.
// ---------------------------------------------------------------------------
__global__ __launch_bounds__(256, 2) void qkv_kernel(
    const float* __restrict__ x, const __hip_bfloat16* __restrict__ Wb,
    const float* __restrict__ bq, const float* __restrict__ bk,
    const float* __restrict__ bv,
    __hip_bfloat16* __restrict__ qb, __hip_bfloat16* __restrict__ kb,
    __hip_bfloat16* __restrict__ vb)
{
  const int b  = blockIdx.y;
  const int n0 = blockIdx.x * 32;
  const int tid = threadIdx.x;
  const int lane = tid & 63;
  const int w = __builtin_amdgcn_readfirstlane(tid >> 6);  // wave 0..3
  const int l15 = lane & 15, quad = lane >> 4;

  __shared__ __align__(16) short Xs[32][264];      // [n][c]
  __shared__ __align__(16) short Vr[4][16][40];    // per-wave v repack

  // stage x-tile: wave w covers c in [w*64, w*64+64)
  const int nloc = lane & 31;
  const float* xrow = x + (size_t)b*CC*NN + n0 + nloc;
#pragma unroll
  for (int cc16 = 0; cc16 < 4; cc16++) {
    int cbase = w*64 + cc16*16 + (lane >> 5)*8;    // 8 consecutive c per lane
    float v[8];
#pragma unroll
    for (int j = 0; j < 8; j++) v[j] = xrow[(size_t)(cbase + j)*NN];
    short8 sv;
#pragma unroll
    for (int j = 0; j < 8; j++) sv[j] = f2bf(v[j]);
    *reinterpret_cast<short8*>(&Xs[nloc][cbase]) = sv;
  }
  __syncthreads();

  const short* wbp = reinterpret_cast<const short*>(Wb);

  for (int jt = 0; jt < 5; jt++) {
    const int rt = w + 4*jt;          // r-tile 0..19 (0,1=q; 2,3=k; 4..19=v)
    short8 Af[8];
#pragma unroll
    for (int kc = 0; kc < 8; kc++)
      Af[kc] = *reinterpret_cast<const short8*>(
          wbp + (size_t)(rt*16 + l15)*CC + kc*32 + quad*8);

    f32x4 a0 = {0.f,0.f,0.f,0.f}, a1 = {0.f,0.f,0.f,0.f};
#pragma unroll
    for (int kc = 0; kc < 8; kc++) {
      short8 B0 = *reinterpret_cast<const short8*>(&Xs[l15][kc*32 + quad*8]);
      short8 B1 = *reinterpret_cast<const short8*>(&Xs[16 + l15][kc*32 + quad*8]);
      a0 = __builtin_amdgcn_mfma_f32_16x16x32_bf16(Af[kc], B0, a0, 0, 0, 0);
      a1 = __builtin_amdgcn_mfma_f32_16x16x32_bf16(Af[kc], B1, a1, 0, 0, 0);
    }
    // D[row=quad*4+r (output row)][col=l15 (n)]
    if (rt < 2) {
#pragma unroll
      for (int r = 0; r < 4; r++) {
        int d = rt*16 + quad*4 + r;
        float bb = bq[d];
        qb[(size_t)b*NN*CQ + (size_t)(n0 + l15)*CQ + d]      = __float2bfloat16(LOG2E*(a0[r] + bb));
        qb[(size_t)b*NN*CQ + (size_t)(n0 + 16 + l15)*CQ + d] = __float2bfloat16(LOG2E*(a1[r] + bb));
      }
    } else if (rt < 4) {
#pragma unroll
      for (int r = 0; r < 4; r++) {
        int d = (rt-2)*16 + quad*4 + r;
        float bb = bk[d];
        kb[(size_t)b*NN*CQ + (size_t)(n0 + l15)*CQ + d]      = __float2bfloat16(a0[r] + bb);
        kb[(size_t)b*NN*CQ + (size_t)(n0 + 16 + l15)*CQ + d] = __float2bfloat16(a1[r] + bb);
      }
    } else {
      const int rv0 = (rt-4)*16;
#pragma unroll
      for (int r = 0; r < 4; r++) {
        float bb = bv[rv0 + quad*4 + r];
        Vr[w][quad*4 + r][l15]      = f2bf(a0[r] + bb);
        Vr[w][quad*4 + r][16 + l15] = f2bf(a1[r] + bb);
      }
      // read back coalesced: 16 rows x 32 n, 64B per row
      short8 t = *reinterpret_cast<const short8*>(&Vr[w][lane >> 2][(lane & 3)*8]);
      *reinterpret_cast<short8*>(
          vb + ((size_t)b*CC + rv0 + (lane >> 2))*NN + n0 + (lane & 3)*8) = t;
    }
  }
}

// ---------------------------------------------------------------------------
// Kernel 2: O = softmax(QK^T) V, epilogue gamma*O + x.
// c-split waves: 4 waves each own a 64-c strip and compute PV for ALL 64
// n-rows -> each staged V element read from LDS exactly ONCE (round-4 read
// it 4x).  P shared across waves via the Ps LDS round-trip.  PV computed
// operand-swapped as O^T = V * P^T (A and B^T share the same verified frag
// layout), so D is [c][n]-oriented -> direct coalesced epilogue stores, no
// transpose LDS.  Double-buffered Vs, reg-prefetch 2 tiles ahead, 2
// barriers/tile; ~46 KB LDS -> 2-3 blocks/CU to overlap barriers.
// NOTE: every acc[] subscript must be compile-time constant (spill trap).
// ---------------------------------------------------------------------------
__global__ __launch_bounds__(256, 2) void attn_kernel(
    const __hip_bfloat16* __restrict__ qb, const __hip_bfloat16* __restrict__ kb,
    const __hip_bfloat16* __restrict__ vb,
    const float* __restrict__ x, const float* __restrict__ gamma,
    float* __restrict__ out)
{
  const int B = blockIdx.x;
  const int b = (B & 7) >> 1;                       // 2 XCDs per batch
  const int n0 = ((B >> 3)*2 + (B & 1)) * 64;       // n-tile 0..63
  const int tid = threadIdx.x;
  const int lane = tid & 63;
  const int w = __builtin_amdgcn_readfirstlane(tid >> 6);   // 0..3
  const int l15 = lane & 15, quad = lane >> 4;
  const int nw = n0 + w*16;                          // S-rows owned by wave

  __shared__ __align__(16) short Vs[2][256][40];     // 40960 B
  __shared__ __align__(16) short Ps[64][40];         // 5120 B
  __shared__ float Lbuf[64];

  const short* qbase = (const short*)qb + (size_t)b*NN*CQ;
  const short* kbase = (const short*)kb + (size_t)b*NN*CQ;
  const short* vbase = (const short*)vb + (size_t)b*CC*NN;

  short8 aq = *(const short8*)(qbase + (size_t)(nw + l15)*CQ + quad*8);

  // V staging map: thread covers rows c_r+64p, 16B chunk mch
  const int c_r = tid >> 2, mch = tid & 3;

#define LOADV(T, D0, D1, D2, D3) { \
    D0 = *(const short8*)(vbase + (size_t)(c_r      )*NN + (T)*32 + mch*8); \
    D1 = *(const short8*)(vbase + (size_t)(c_r +  64)*NN + (T)*32 + mch*8); \
    D2 = *(const short8*)(vbase + (size_t)(c_r + 128)*NN + (T)*32 + mch*8); \
    D3 = *(const short8*)(vbase + (size_t)(c_r + 192)*NN + (T)*32 + mch*8); }
#define WRITEV(BUF, S0, S1, S2, S3) { \
    *(short8*)(&Vs[BUF][c_r      ][mch*8]) = S0; \
    *(short8*)(&Vs[BUF][c_r +  64][mch*8]) = S1; \
    *(short8*)(&Vs[BUF][c_r + 128][mch*8]) = S2; \
    *(short8*)(&Vs[BUF][c_r + 192][mch*8]) = S3; }
#define LOADK(T, K0, K1) { \
    K0 = *(const short8*)(kbase + (size_t)((T)*32 + l15)*CQ + quad*8); \
    K1 = *(const short8*)(kbase + (size_t)((T)*32 + 16 + l15)*CQ + quad*8); }

  short8 va0, va1, va2, va3, vb0, vb1, vb2, vb3;
  short8 kA0, kA1, kB0, kB1;

  LOADV(0, va0, va1, va2, va3);
  LOADK(0, kA0, kA1);
  WRITEV(0, va0, va1, va2, va3);
  LOADV(1, vb0, vb1, vb2, vb3);
  LOADK(1, kB0, kB1);

  f32x4 acc[4][4];   // [cg][ng], rows=c, cols=n
#pragma unroll
  for (int cg = 0; cg < 4; cg++)
#pragma unroll
    for (int ng = 0; ng < 4; ng++) acc[cg][ng] = (f32x4){0.f,0.f,0.f,0.f};
  float lsum[4] = {0.f,0.f,0.f,0.f};

  __syncthreads();

#define STEP(T, KF0, KF1, BUF, W0, W1, W2, W3, L0, L1, L2, L3, LK0, LK1) { \
    f32x4 z = {0.f,0.f,0.f,0.f}; \
    f32x4 S0 = __builtin_amdgcn_mfma_f32_16x16x32_bf16(aq, KF0, z, 0,0,0); \
    f32x4 S1 = __builtin_amdgcn_mfma_f32_16x16x32_bf16(aq, KF1, z, 0,0,0); \
    _Pragma("unroll") \
    for (int r = 0; r < 4; r++) { \
      float e0 = __builtin_amdgcn_exp2f(S0[r]); \
      float e1 = __builtin_amdgcn_exp2f(S1[r]); \
      lsum[r] += e0 + e1; \
      Ps[w*16 + quad*4 + r][l15]      = f2bf(e0); \
      Ps[w*16 + quad*4 + r][16 + l15] = f2bf(e1); \
    } \
    if ((T) + 1 < 128) { WRITEV((BUF)^1, W0, W1, W2, W3); } \
    if ((T) + 2 < 128) { LOADV((T)+2, L0, L1, L2, L3); LOADK((T)+2, LK0, LK1); } \
    __syncthreads(); \
    short8 ap0 = *(const short8*)(&Ps[     l15][quad*8]); \
    short8 ap1 = *(const short8*)(&Ps[16 + l15][quad*8]); \
    short8 ap2 = *(const short8*)(&Ps[32 + l15][quad*8]); \
    short8 ap3 = *(const short8*)(&Ps[48 + l15][quad*8]); \
    _Pragma("unroll") \
    for (int cg = 0; cg < 4; cg++) { \
      short8 bvf = *(const short8*)(&Vs[BUF][w*64 + cg*16 + l15][quad*8]); \
      acc[cg][0] = __builtin_amdgcn_mfma_f32_16x16x32_bf16(bvf, ap0, acc[cg][0], 0,0,0); \
      acc[cg][1] = __builtin_amdgcn_mfma_f32_16x16x32_bf16(bvf, ap1, acc[cg][1], 0,0,0); \
      acc[cg][2] = __builtin_amdgcn_mfma_f32_16x16x32_bf16(bvf, ap2, acc[cg][2], 0,0,0); \
      acc[cg][3] = __builtin_amdgcn_mfma_f32_16x16x32_bf16(bvf, ap3, acc[cg][3], 0,0,0); \
    } \
    __syncthreads(); }

  for (int i = 0; i < 128; i += 2) {
    STEP(i,   kA0, kA1, 0, vb0, vb1, vb2, vb3, va0, va1, va2, va3, kA0, kA1);
    STEP(i+1, kB0, kB1, 1, va0, va1, va2, va3, vb0, vb1, vb2, vb3, kB0, kB1);
  }

  // row sums -> Lbuf (inverse), shared to all waves
#pragma unroll
  for (int r = 0; r < 4; r++) {
    float s = lsum[r];
    s += __shfl_xor(s, 1); s += __shfl_xor(s, 2);
    s += __shfl_xor(s, 4); s += __shfl_xor(s, 8);
    if (l15 == 0) Lbuf[w*16 + quad*4 + r] = 1.0f / s;
  }
  __syncthreads();

  // epilogue: acc[cg][ng] holds O^T rows c = w*64+cg*16+quad*4+r,
  // cols n = n0+ng*16+l15 -> direct coalesced stores
  const float gm = gamma[0];
  float Lv[4];
#pragma unroll
  for (int ng = 0; ng < 4; ng++) Lv[ng] = Lbuf[ng*16 + l15];
#pragma unroll
  for (int cg = 0; cg < 4; cg++) {
#pragma unroll
    for (int ng = 0; ng < 4; ng++) {
#pragma unroll
      for (int r = 0; r < 4; r++) {
        size_t idx = ((size_t)b*CC + w*64 + cg*16 + quad*4 + r)*NN + n0 + ng*16 + l15;
        out[idx] = gm * acc[cg][ng][r] * Lv[ng] + x[idx];
      }
    }
  }
}

// ---------------------------------------------------------------------------
extern "C" void kernel_launch(void* const* d_in, const int* in_sizes, int n_in,
                              void* d_out, int out_size, void* d_ws, size_t ws_size,
                              hipStream_t stream) {
  const float* x     = (const float*)d_in[0];
  const float* Wq    = (const float*)d_in[1];
  const float* bq    = (const float*)d_in[2];
  const float* Wk    = (const float*)d_in[3];
  const float* bk    = (const float*)d_in[4];
  const float* Wv    = (const float*)d_in[5];
  const float* bv    = (const float*)d_in[6];
  const float* gamma = (const float*)d_in[7];
  float* out = (float*)d_out;

  char* ws = (char*)d_ws;
  if (ws_size < (11u << 20)) return;
  __hip_bfloat16* qb = (__hip_bfloat16*)(ws);                 // [B][N][32]  1 MB
  __hip_bfloat16* kb = (__hip_bfloat16*)(ws + (1u << 20));    // [B][N][32]  1 MB
  __hip_bfloat16* vb = (__hip_bfloat16*)(ws + (2u << 20));    // [B][C][N]   8 MB
  __hip_bfloat16* Wb = (__hip_bfloat16*)(ws + (10u << 20));   // [320][256]  160 KB

  prep_kernel<<<dim3(40), 256, 0, stream>>>(Wq, Wk, Wv, Wb);
  qkv_kernel<<<dim3(128, 4), 256, 0, stream>>>(x, Wb, bq, bk, bv, qb, kb, vb);
  attn_kernel<<<dim3(256), 256, 0, stream>>>(qb, kb, vb, x, gamma, out);
}

// Round 6
// 155.552 us; speedup vs baseline: 4.1039x; 1.1435x over previous
//
#include <hip/hip_runtime.h>
#include <hip/hip_bf16.h>

#define CC 256
#define NN 4096
#define CQ 32
#define LOG2E 1.4426950408889634f

using short8 = __attribute__((ext_vector_type(8))) short;
using f32x4  = __attribute__((ext_vector_type(4))) float;

static __device__ __forceinline__ short f2bf(float f) {
  __hip_bfloat16 h = __float2bfloat16(f);
  return *reinterpret_cast<short*>(&h);
}

// ---------------------------------------------------------------------------
// Kernel 0: build Wf = W (Wq|Wk|Wv rows concat, 320x256) in FRAG-LINEAR bf16
// layout: Wf[((tile*8 + kc)*64 + lane)*8 + j] = W[tile*16 + (lane&15)]
//                                               [kc*32 + (lane>>4)*8 + j]
// so a wave's A-frag load in qkv is one contiguous 1 KB read.
// ---------------------------------------------------------------------------
__global__ __launch_bounds__(256) void prep_kernel(
    const float* __restrict__ Wq, const float* __restrict__ Wk,
    const float* __restrict__ Wv, __hip_bfloat16* __restrict__ Wf)
{
  int t = blockIdx.x*256 + threadIdx.x;          // 0..10239
  int lane = t & 63, frag = t >> 6;              // frag = tile*8 + kc
  int tile = frag >> 3, kc = frag & 7;
  int l15 = lane & 15, quad = lane >> 4;
  int R = tile*16 + l15;                         // global output row 0..319
  int k0 = kc*32 + quad*8;
  const float* src;
  if (R < 32)       src = Wq + (size_t)R*CC + k0;
  else if (R < 64)  src = Wk + (size_t)(R-32)*CC + k0;
  else              src = Wv + (size_t)(R-64)*CC + k0;
  float4 a = *(const float4*)(src);
  float4 c = *(const float4*)(src + 4);
  short8 o;
  o[0]=f2bf(a.x); o[1]=f2bf(a.y); o[2]=f2bf(a.z); o[3]=f2bf(a.w);
  o[4]=f2bf(c.x); o[5]=f2bf(c.y); o[6]=f2bf(c.z); o[7]=f2bf(c.w);
  *reinterpret_cast<short8*>(reinterpret_cast<short*>(Wf) + (size_t)t*8) = o;
}

// ---------------------------------------------------------------------------
// Kernel 1: QKV via MFMA, x-stationary.  512 threads (8 waves), grid 64x4
// = 256 blocks = 8 waves/CU = 2/SIMD.  Stage x[256c x 64n] -> LDS bf16
// [n][c]; wave w computes r-tiles {2w, 2w+1} (+ tile 16+w for w<4).
// A-frags are contiguous 1KB loads from frag-linear Wf.  v output repacked
// via per-wave LDS -> coalesced 16B stores.
// ---------------------------------------------------------------------------
__global__ __launch_bounds__(512, 2) void qkv_kernel(
    const float* __restrict__ x, const __hip_bfloat16* __restrict__ Wf,
    const float* __restrict__ bq, const float* __restrict__ bk,
    const float* __restrict__ bv,
    __hip_bfloat16* __restrict__ qb, __hip_bfloat16* __restrict__ kb,
    __hip_bfloat16* __restrict__ vb)
{
  const int b  = blockIdx.y;
  const int n0 = blockIdx.x * 64;
  const int tid = threadIdx.x;
  const int lane = tid & 63;
  const int w = __builtin_amdgcn_readfirstlane(tid >> 6);  // wave 0..7
  const int l15 = lane & 15, quad = lane >> 4;

  __shared__ __align__(16) short Xs[64][264];     // [n][c] bf16, 33792 B
  __shared__ __align__(16) short Vr[8][16][72];   // per-wave repack, 18432 B

  // ---- stage x tile: thread covers n = tid&63, 8-c runs ----
  const int sn = tid & 63, cg8 = tid >> 6;
  const float* xcol = x + (size_t)b*CC*NN + n0 + sn;
#pragma unroll
  for (int it = 0; it < 4; it++) {
    int cbase = it*64 + cg8*8;
    float v[8];
#pragma unroll
    for (int j = 0; j < 8; j++) v[j] = xcol[(size_t)(cbase + j)*NN];
    short8 sv;
#pragma unroll
    for (int j = 0; j < 8; j++) sv[j] = f2bf(v[j]);
    *reinterpret_cast<short8*>(&Xs[sn][cbase]) = sv;
  }
  __syncthreads();

  const short* wfp = reinterpret_cast<const short*>(Wf);

#define QKV_TILE(T) { \
    const int t_ = (T); \
    short8 Af[8]; \
    _Pragma("unroll") \
    for (int kc = 0; kc < 8; kc++) \
      Af[kc] = *(const short8*)(wfp + ((size_t)(t_*8 + kc)*64 + lane)*8); \
    f32x4 ac0 = {0.f,0.f,0.f,0.f}, ac1 = {0.f,0.f,0.f,0.f}; \
    f32x4 ac2 = {0.f,0.f,0.f,0.f}, ac3 = {0.f,0.f,0.f,0.f}; \
    _Pragma("unroll") \
    for (int kc = 0; kc < 8; kc++) { \
      short8 B0 = *(const short8*)(&Xs[     l15][kc*32 + quad*8]); \
      short8 B1 = *(const short8*)(&Xs[16 + l15][kc*32 + quad*8]); \
      short8 B2 = *(const short8*)(&Xs[32 + l15][kc*32 + quad*8]); \
      short8 B3 = *(const short8*)(&Xs[48 + l15][kc*32 + quad*8]); \
      ac0 = __builtin_amdgcn_mfma_f32_16x16x32_bf16(Af[kc], B0, ac0, 0,0,0); \
      ac1 = __builtin_amdgcn_mfma_f32_16x16x32_bf16(Af[kc], B1, ac1, 0,0,0); \
      ac2 = __builtin_amdgcn_mfma_f32_16x16x32_bf16(Af[kc], B2, ac2, 0,0,0); \
      ac3 = __builtin_amdgcn_mfma_f32_16x16x32_bf16(Af[kc], B3, ac3, 0,0,0); \
    } \
    if (t_ < 2) { \
      int d0 = t_*16; \
      _Pragma("unroll") \
      for (int r = 0; r < 4; r++) { \
        int d = d0 + quad*4 + r; float bb = bq[d]; \
        qb[(size_t)b*NN*CQ + (size_t)(n0      + l15)*CQ + d] = __float2bfloat16(LOG2E*(ac0[r] + bb)); \
        qb[(size_t)b*NN*CQ + (size_t)(n0 + 16 + l15)*CQ + d] = __float2bfloat16(LOG2E*(ac1[r] + bb)); \
        qb[(size_t)b*NN*CQ + (size_t)(n0 + 32 + l15)*CQ + d] = __float2bfloat16(LOG2E*(ac2[r] + bb)); \
        qb[(size_t)b*NN*CQ + (size_t)(n0 + 48 + l15)*CQ + d] = __float2bfloat16(LOG2E*(ac3[r] + bb)); \
      } \
    } else if (t_ < 4) { \
      int d0 = (t_-2)*16; \
      _Pragma("unroll") \
      for (int r = 0; r < 4; r++) { \
        int d = d0 + quad*4 + r; float bb = bk[d]; \
        kb[(size_t)b*NN*CQ + (size_t)(n0      + l15)*CQ + d] = __float2bfloat16(ac0[r] + bb); \
        kb[(size_t)b*NN*CQ + (size_t)(n0 + 16 + l15)*CQ + d] = __float2bfloat16(ac1[r] + bb); \
        kb[(size_t)b*NN*CQ + (size_t)(n0 + 32 + l15)*CQ + d] = __float2bfloat16(ac2[r] + bb); \
        kb[(size_t)b*NN*CQ + (size_t)(n0 + 48 + l15)*CQ + d] = __float2bfloat16(ac3[r] + bb); \
      } \
    } else { \
      int rv0 = (t_-4)*16; \
      _Pragma("unroll") \
      for (int r = 0; r < 4; r++) { \
        float bb = bv[rv0 + quad*4 + r]; \
        Vr[w][quad*4 + r][     l15] = f2bf(ac0[r] + bb); \
        Vr[w][quad*4 + r][16 + l15] = f2bf(ac1[r] + bb); \
        Vr[w][quad*4 + r][32 + l15] = f2bf(ac2[r] + bb); \
        Vr[w][quad*4 + r][48 + l15] = f2bf(ac3[r] + bb); \
      } \
      int row = lane >> 2, cb = (lane & 3)*16; \
      short8 t0 = *(const short8*)(&Vr[w][row][cb]); \
      short8 t1 = *(const short8*)(&Vr[w][row][cb + 8]); \
      *(short8*)(vb + ((size_t)b*CC + rv0 + row)*NN + n0 + cb)     = t0; \
      *(short8*)(vb + ((size_t)b*CC + rv0 + row)*NN + n0 + cb + 8) = t1; \
    } }

  QKV_TILE(2*w);
  QKV_TILE(2*w + 1);
  if (w < 4) { QKV_TILE(16 + w); }
#undef QKV_TILE
}

// ---------------------------------------------------------------------------
// Kernel 2: O = softmax(QK^T) V, epilogue gamma*O + x.  512 threads, 8 waves
// = 2/SIMD.  m-tile = 64, wave (sg,mh): S rows sg*16 x m-half mh (32m); PV:
// wave (cs=sg, mh): O^T strip 64c x 64n over K=32 (its m-half), acc[4][4];
// mh pairs combined via LDS at the end.  Single Vs buffer, 2 barriers/tile,
// register prefetch of tile T+1.  All acc[] subscripts compile-time const.
// ---------------------------------------------------------------------------
__global__ __launch_bounds__(512, 2) void attn_kernel(
    const __hip_bfloat16* __restrict__ qb, const __hip_bfloat16* __restrict__ kb,
    const __hip_bfloat16* __restrict__ vb,
    const float* __restrict__ x, const float* __restrict__ gamma,
    float* __restrict__ out)
{
  const int Bk = blockIdx.x;
  const int b = (Bk & 7) >> 1;                       // 2 XCDs per batch
  const int n0 = ((Bk >> 3)*2 + (Bk & 1)) * 64;      // n-tile 0..63
  const int tid = threadIdx.x;
  const int lane = tid & 63;
  const int w = __builtin_amdgcn_readfirstlane(tid >> 6);   // 0..7
  const int sg = w & 3;                               // S row-group / c-strip
  const int mh = w >> 2;                              // m-half 0/1
  const int l15 = lane & 15, quad = lane >> 4;

  __shared__ __align__(16) short Vs[256][72];   // [c][m 0..64], 36864 B
  __shared__ __align__(16) short Ps[64][72];    // [n][m 0..64], 9216 B
  __shared__ float Lbuf2[2][64];

  const short* qbase = (const short*)qb + (size_t)b*NN*CQ;
  const short* kbase = (const short*)kb + (size_t)b*NN*CQ;
  const short* vbase = (const short*)vb + (size_t)b*CC*NN;

  short8 aq = *(const short8*)(qbase + (size_t)(n0 + sg*16 + l15)*CQ + quad*8);

  // V staging: thread covers row vr, m-half sh (32 shorts = 4 chunks)
  const int vr = tid >> 1, sh = tid & 1;

  short8 vf0, vf1, vf2, vf3, kf0, kf1;
  // preload tile 0
#pragma unroll
  for (int j = 0; j < 4; j++) {
    short8 t = *(const short8*)(vbase + (size_t)vr*NN + sh*32 + j*8);
    if (j == 0) vf0 = t; else if (j == 1) vf1 = t; else if (j == 2) vf2 = t; else vf3 = t;
  }
  kf0 = *(const short8*)(kbase + (size_t)(mh*32 +      l15)*CQ + quad*8);
  kf1 = *(const short8*)(kbase + (size_t)(mh*32 + 16 + l15)*CQ + quad*8);
  *(short8*)(&Vs[vr][sh*32 +  0]) = vf0;
  *(short8*)(&Vs[vr][sh*32 +  8]) = vf1;
  *(short8*)(&Vs[vr][sh*32 + 16]) = vf2;
  *(short8*)(&Vs[vr][sh*32 + 24]) = vf3;

  f32x4 acc[4][4];
#pragma unroll
  for (int cg = 0; cg < 4; cg++)
#pragma unroll
    for (int ng = 0; ng < 4; ng++) acc[cg][ng] = (f32x4){0.f,0.f,0.f,0.f};
  float lsum[4] = {0.f,0.f,0.f,0.f};

  __syncthreads();

  for (int T = 0; T < 64; T++) {
    // prefetch tile T+1 into regs
    short8 nv0, nv1, nv2, nv3, nk0, nk1;
    if (T < 63) {
      const short* vp = vbase + (size_t)vr*NN + (T+1)*64 + sh*32;
      nv0 = *(const short8*)(vp);
      nv1 = *(const short8*)(vp + 8);
      nv2 = *(const short8*)(vp + 16);
      nv3 = *(const short8*)(vp + 24);
      nk0 = *(const short8*)(kbase + (size_t)((T+1)*64 + mh*32 +      l15)*CQ + quad*8);
      nk1 = *(const short8*)(kbase + (size_t)((T+1)*64 + mh*32 + 16 + l15)*CQ + quad*8);
    }

    // S' for rows sg*16.., m-half mh
    f32x4 z = {0.f,0.f,0.f,0.f};
    f32x4 S0 = __builtin_amdgcn_mfma_f32_16x16x32_bf16(aq, kf0, z, 0,0,0);
    f32x4 S1 = __builtin_amdgcn_mfma_f32_16x16x32_bf16(aq, kf1, z, 0,0,0);
#pragma unroll
    for (int r = 0; r < 4; r++) {
      float e0 = __builtin_amdgcn_exp2f(S0[r]);
      float e1 = __builtin_amdgcn_exp2f(S1[r]);
      lsum[r] += e0 + e1;
      Ps[sg*16 + quad*4 + r][mh*32 +      l15] = f2bf(e0);
      Ps[sg*16 + quad*4 + r][mh*32 + 16 + l15] = f2bf(e1);
    }
    __syncthreads();   // Ps(T) + Vs(T) visible to all

    short8 ap0 = *(const short8*)(&Ps[     l15][mh*32 + quad*8]);
    short8 ap1 = *(const short8*)(&Ps[16 + l15][mh*32 + quad*8]);
    short8 ap2 = *(const short8*)(&Ps[32 + l15][mh*32 + quad*8]);
    short8 ap3 = *(const short8*)(&Ps[48 + l15][mh*32 + quad*8]);
#pragma unroll
    for (int cg = 0; cg < 4; cg++) {
      short8 av = *(const short8*)(&Vs[sg*64 + cg*16 + l15][mh*32 + quad*8]);
      acc[cg][0] = __builtin_amdgcn_mfma_f32_16x16x32_bf16(av, ap0, acc[cg][0], 0,0,0);
      acc[cg][1] = __builtin_amdgcn_mfma_f32_16x16x32_bf16(av, ap1, acc[cg][1], 0,0,0);
      acc[cg][2] = __builtin_amdgcn_mfma_f32_16x16x32_bf16(av, ap2, acc[cg][2], 0,0,0);
      acc[cg][3] = __builtin_amdgcn_mfma_f32_16x16x32_bf16(av, ap3, acc[cg][3], 0,0,0);
    }
    __syncthreads();   // everyone done reading Vs/Ps of tile T

    if (T < 63) {
      *(short8*)(&Vs[vr][sh*32 +  0]) = nv0;
      *(short8*)(&Vs[vr][sh*32 +  8]) = nv1;
      *(short8*)(&Vs[vr][sh*32 + 16]) = nv2;
      *(short8*)(&Vs[vr][sh*32 + 24]) = nv3;
      kf0 = nk0; kf1 = nk1;
    }
  }

  // ---- L: reduce over l15, publish per m-half ----
#pragma unroll
  for (int r = 0; r < 4; r++) {
    float s = lsum[r];
    s += __shfl_xor(s, 1); s += __shfl_xor(s, 2);
    s += __shfl_xor(s, 4); s += __shfl_xor(s, 8);
    if (l15 == 0) Lbuf2[mh][sg*16 + quad*4 + r] = s;
  }

  // ---- combine mh halves of acc via LDS (2 rounds of 2 c-strips) ----
  float* poolf = reinterpret_cast<float*>(&Vs[0][0]);   // 32 KB of the 36 KB Vs
  __syncthreads();
#pragma unroll
  for (int g = 0; g < 2; g++) {
    if (mh == 1 && (sg >> 1) == g) {
#pragma unroll
      for (int cg = 0; cg < 4; cg++)
#pragma unroll
        for (int ng = 0; ng < 4; ng++)
#pragma unroll
          for (int r = 0; r < 4; r++)
            poolf[(sg & 1)*4096 + (cg*16 + quad*4 + r)*64 + ng*16 + l15] = acc[cg][ng][r];
    }
    __syncthreads();
    if (mh == 0 && (sg >> 1) == g) {
#pragma unroll
      for (int cg = 0; cg < 4; cg++)
#pragma unroll
        for (int ng = 0; ng < 4; ng++)
#pragma unroll
          for (int r = 0; r < 4; r++)
            acc[cg][ng][r] += poolf[(sg & 1)*4096 + (cg*16 + quad*4 + r)*64 + ng*16 + l15];
    }
    __syncthreads();
  }

  // ---- epilogue (mh==0 waves): out = gamma*O/l + x, coalesced rows ----
  if (mh == 0) {
    const float gm = gamma[0];
    float Lv[4];
#pragma unroll
    for (int ng = 0; ng < 4; ng++)
      Lv[ng] = 1.0f / (Lbuf2[0][ng*16 + l15] + Lbuf2[1][ng*16 + l15]);
#pragma unroll
    for (int cg = 0; cg < 4; cg++) {
#pragma unroll
      for (int ng = 0; ng < 4; ng++) {
#pragma unroll
        for (int r = 0; r < 4; r++) {
          size_t idx = ((size_t)b*CC + sg*64 + cg*16 + quad*4 + r)*NN + n0 + ng*16 + l15;
          out[idx] = gm * acc[cg][ng][r] * Lv[ng] + x[idx];
        }
      }
    }
  }
}

// ---------------------------------------------------------------------------
extern "C" void kernel_launch(void* const* d_in, const int* in_sizes, int n_in,
                              void* d_out, int out_size, void* d_ws, size_t ws_size,
                              hipStream_t stream) {
  const float* x     = (const float*)d_in[0];
  const float* Wq    = (const float*)d_in[1];
  const float* bq    = (const float*)d_in[2];
  const float* Wk    = (const float*)d_in[3];
  const float* bk    = (const float*)d_in[4];
  const float* Wv    = (const float*)d_in[5];
  const float* bv    = (const float*)d_in[6];
  const float* gamma = (const float*)d_in[7];
  float* out = (float*)d_out;

  char* ws = (char*)d_ws;
  if (ws_size < (11u << 20)) return;
  __hip_bfloat16* qb = (__hip_bfloat16*)(ws);                 // [B][N][32]  1 MB
  __hip_bfloat16* kb = (__hip_bfloat16*)(ws + (1u << 20));    // [B][N][32]  1 MB
  __hip_bfloat16* vb = (__hip_bfloat16*)(ws + (2u << 20));    // [B][C][N]   8 MB
  __hip_bfloat16* Wf = (__hip_bfloat16*)(ws + (10u << 20));   // frag-linear 160 KB

  prep_kernel<<<dim3(40), 256, 0, stream>>>(Wq, Wk, Wv, Wf);
  qkv_kernel<<<dim3(64, 4), 512, 0, stream>>>(x, Wf, bq, bk, bv, qb, kb, vb);
  attn_kernel<<<dim3(256), 512, 0, stream>>>(qb, kb, vb, x, gamma, out);
}